// Round 1
// 547.507 us; speedup vs baseline: 1.0390x; 1.0390x over previous
//
#include <hip/hip_runtime.h>

// Problem constants
constexpr int NN   = 50000;
constexpr int EE   = 800000;
constexpr int INF  = 128;   // input feat
constexpr int NH   = 4;     // heads

__device__ __forceinline__ float elw(float a) {
    a = (a > 0.f) ? a : 0.2f * a;          // leaky_relu(0.2)
    return __expf(a);                       // exp without max-sub (scores bounded)
}

// ---------- Tiled fp32 GEMM (64x64, 4x4): used for the small PQ GEMM ----------
__global__ __launch_bounds__(256) void gemm_tiled(const float* __restrict__ A,
                                                  const float* __restrict__ B,
                                                  float* __restrict__ C,
                                                  int N, int K, int M) {
    __shared__ float As[16][68];   // [k][row], padded
    __shared__ float Bs[16][64];   // [k][col]
    const int tid = threadIdx.x;
    const int tx = tid & 15, ty = tid >> 4;
    const int row0 = blockIdx.x * 64, col0 = blockIdx.y * 64;

    float acc[4][4] = {};

    for (int k0 = 0; k0 < K; k0 += 16) {
        {
            const int a_row = tid >> 2;
            const int a_k   = (tid & 3) * 4;
            const int gr    = row0 + a_row;
            float4 v = make_float4(0.f, 0.f, 0.f, 0.f);
            if (gr < N) v = *(const float4*)(A + (size_t)gr * K + k0 + a_k);
            As[a_k + 0][a_row] = v.x;
            As[a_k + 1][a_row] = v.y;
            As[a_k + 2][a_row] = v.z;
            As[a_k + 3][a_row] = v.w;
        }
        {
            const int b_k = tid >> 4;
            const int b_c = (tid & 15) * 4;
            float4 w = *(const float4*)(B + (size_t)(k0 + b_k) * M + col0 + b_c);
            *(float4*)&Bs[b_k][b_c] = w;
        }
        __syncthreads();
        #pragma unroll
        for (int kk = 0; kk < 16; ++kk) {
            float4 a = *(const float4*)&As[kk][ty * 4];
            float4 b = *(const float4*)&Bs[kk][tx * 4];
            const float av[4] = {a.x, a.y, a.z, a.w};
            const float bv[4] = {b.x, b.y, b.z, b.w};
            #pragma unroll
            for (int i = 0; i < 4; ++i)
                #pragma unroll
                for (int j = 0; j < 4; ++j)
                    acc[i][j] = fmaf(av[i], bv[j], acc[i][j]);
        }
        __syncthreads();
    }
    #pragma unroll
    for (int i = 0; i < 4; ++i) {
        const int r = row0 + ty * 4 + i;
        if (r < N) {
            float* cp = C + (size_t)r * M + col0 + tx * 4;
            cp[0] = acc[i][0]; cp[1] = acc[i][1]; cp[2] = acc[i][2]; cp[3] = acc[i][3];
        }
    }
}

// ---------- Tiled fp32 GEMM (64-tile) with fused attention-score epilogue ----------
template <int CH>
__global__ __launch_bounds__(256) void gemm_att(const float* __restrict__ A,
                                                const float* __restrict__ B,
                                                float* __restrict__ C,
                                                const float* __restrict__ att_s,
                                                const float* __restrict__ att_d,
                                                float* __restrict__ a_s,
                                                float* __restrict__ a_d,
                                                int N, int K, int M) {
    __shared__ float As[16][68];   // [k][row], padded
    __shared__ float Bs[16][64];   // [k][col]
    const int tid = threadIdx.x;
    const int tx = tid & 15, ty = tid >> 4;
    const int row0 = blockIdx.x * 64, col0 = blockIdx.y * 64;

    const int col  = col0 + tx * 4;
    const int head = col / CH;
    const int pos  = col % CH;
    float attS[4], attD[4];
    #pragma unroll
    for (int j = 0; j < 4; ++j) {
        attS[j] = att_s[head * CH + pos + j];
        attD[j] = att_d[head * CH + pos + j];
    }

    float acc[4][4] = {};

    for (int k0 = 0; k0 < K; k0 += 16) {
        {
            const int a_row = tid >> 2;
            const int a_k   = (tid & 3) * 4;
            const int gr    = row0 + a_row;
            float4 v = make_float4(0.f, 0.f, 0.f, 0.f);
            if (gr < N) v = *(const float4*)(A + (size_t)gr * K + k0 + a_k);
            As[a_k + 0][a_row] = v.x;
            As[a_k + 1][a_row] = v.y;
            As[a_k + 2][a_row] = v.z;
            As[a_k + 3][a_row] = v.w;
        }
        {
            const int b_k = tid >> 4;
            const int b_c = (tid & 15) * 4;
            float4 w = *(const float4*)(B + (size_t)(k0 + b_k) * M + col0 + b_c);
            *(float4*)&Bs[b_k][b_c] = w;
        }
        __syncthreads();
        #pragma unroll
        for (int kk = 0; kk < 16; ++kk) {
            float4 a = *(const float4*)&As[kk][ty * 4];
            float4 b = *(const float4*)&Bs[kk][tx * 4];
            const float av[4] = {a.x, a.y, a.z, a.w};
            const float bv[4] = {b.x, b.y, b.z, b.w};
            #pragma unroll
            for (int i = 0; i < 4; ++i)
                #pragma unroll
                for (int j = 0; j < 4; ++j)
                    acc[i][j] = fmaf(av[i], bv[j], acc[i][j]);
        }
        __syncthreads();
    }
    #pragma unroll
    for (int i = 0; i < 4; ++i) {
        const int r = row0 + ty * 4 + i;
        if (r < N) {
            float* cp = C + (size_t)r * M + col0 + tx * 4;
            cp[0] = acc[i][0]; cp[1] = acc[i][1]; cp[2] = acc[i][2]; cp[3] = acc[i][3];
        }
        float ss = 0.f, sd = 0.f;
        #pragma unroll
        for (int j = 0; j < 4; ++j) {
            ss = fmaf(acc[i][j], attS[j], ss);
            sd = fmaf(acc[i][j], attD[j], sd);
        }
        #pragma unroll
        for (int msk = 1; msk < CH / 4; msk <<= 1) {
            ss += __shfl_xor(ss, msk, 64);
            sd += __shfl_xor(sd, msk, 64);
        }
        if ((tx & (CH / 4 - 1)) == 0 && r < N) {
            a_s[r * NH + head] = ss;
            a_d[r * NH + head] = sd;
        }
    }
}

// ---------- CSR build ----------
__global__ __launch_bounds__(256) void count_deg_k(const int* __restrict__ ei,
                                                   int* __restrict__ deg) {
    const int e = blockIdx.x * 256 + threadIdx.x;
    if (e < EE) atomicAdd(&deg[ei[EE + e]], 1);
}

// single-block exclusive scan over deg[0..NN) -> rowptr[0..NN], cursor copy
__global__ __launch_bounds__(1024) void scan_k(const int* __restrict__ deg,
                                               int* __restrict__ rowptr,
                                               int* __restrict__ cursor) {
    __shared__ int wsum[16];
    const int tid = threadIdx.x;
    const int lane = tid & 63, wv = tid >> 6;
    int total = 0;
    for (int base = 0; base < NN; base += 1024) {
        const int i = base + tid;
        const int v = (i < NN) ? deg[i] : 0;
        int incl = v;
        #pragma unroll
        for (int d = 1; d < 64; d <<= 1) {
            int t = __shfl_up(incl, d, 64);
            if (lane >= d) incl += t;
        }
        if (lane == 63) wsum[wv] = incl;
        __syncthreads();
        if (wv == 0) {
            int s = (lane < 16) ? wsum[lane] : 0;
            #pragma unroll
            for (int d = 1; d < 16; d <<= 1) {
                int t = __shfl_up(s, d, 64);
                if (lane >= d) s += t;
            }
            if (lane < 16) wsum[lane] = s;
        }
        __syncthreads();
        const int excl = total + (wv > 0 ? wsum[wv - 1] : 0) + incl - v;
        const int chunk = wsum[15];
        if (i < NN) { rowptr[i] = excl; cursor[i] = excl; }
        total += chunk;
        __syncthreads();   // protect wsum before next iteration's writes
    }
    if (tid == 0) rowptr[NN] = total;
}

__global__ __launch_bounds__(256) void scatter_perm_k(const int* __restrict__ ei,
                                                      int* __restrict__ cursor,
                                                      int* __restrict__ perm,
                                                      int* __restrict__ psrc,
                                                      int* __restrict__ pdst) {
    const int e = blockIdx.x * 256 + threadIdx.x;
    if (e >= EE) return;
    const int d = ei[EE + e];
    const int p = atomicAdd(&cursor[d], 1);
    perm[p] = e;
    psrc[p] = ei[e];
    pdst[p] = d;
}

// ---------- Layer 1: SINGLE-PASS softmax+aggregate (post-normalization), HC=256 ----------
// One wave per dst node. lane = channel-quad, hh = lane>>4 = head.
// w = exp(leaky(a_s[src]+a_d[dst])) accumulated unnormalized; divide by sum at end.
// Mathematically identical to max-subtracted softmax (scores bounded << 88).
__global__ __launch_bounds__(256) void softagg1(const int* __restrict__ rowptr,
                                                const int* __restrict__ psrc,
                                                const float* __restrict__ a_s,
                                                const float* __restrict__ a_d,
                                                const float* __restrict__ xl,
                                                const float* __restrict__ bias,
                                                float* __restrict__ out) {
    const int wv = threadIdx.x >> 6, lane = threadIdx.x & 63;
    const int n = blockIdx.x * 4 + wv;
    if (n >= NN) return;
    const int r0 = rowptr[n], r1 = rowptr[n + 1];
    const int hh = lane >> 4;
    const float ad = a_d[n * NH + hh];

    const float4* X4 = (const float4*)xl;   // row stride 64 float4
    float4 A0 = {0,0,0,0}, A1 = {0,0,0,0}, A2 = {0,0,0,0}, A3 = {0,0,0,0};
    float sum = 0.f;
    int j = r0;
    for (; j + 7 < r1; j += 8) {
        const int s0 = psrc[j],     s1 = psrc[j + 1], s2 = psrc[j + 2], s3 = psrc[j + 3];
        const int s4 = psrc[j + 4], s5 = psrc[j + 5], s6 = psrc[j + 6], s7 = psrc[j + 7];
        const float w0 = elw(a_s[s0 * NH + hh] + ad);
        const float w1 = elw(a_s[s1 * NH + hh] + ad);
        const float w2 = elw(a_s[s2 * NH + hh] + ad);
        const float w3 = elw(a_s[s3 * NH + hh] + ad);
        const float w4 = elw(a_s[s4 * NH + hh] + ad);
        const float w5 = elw(a_s[s5 * NH + hh] + ad);
        const float w6 = elw(a_s[s6 * NH + hh] + ad);
        const float w7 = elw(a_s[s7 * NH + hh] + ad);
        sum += ((w0 + w1) + (w2 + w3)) + ((w4 + w5) + (w6 + w7));
        const float4 v0 = X4[(size_t)s0 * 64 + lane];
        const float4 v1 = X4[(size_t)s1 * 64 + lane];
        const float4 v2 = X4[(size_t)s2 * 64 + lane];
        const float4 v3 = X4[(size_t)s3 * 64 + lane];
        const float4 v4 = X4[(size_t)s4 * 64 + lane];
        const float4 v5 = X4[(size_t)s5 * 64 + lane];
        const float4 v6 = X4[(size_t)s6 * 64 + lane];
        const float4 v7 = X4[(size_t)s7 * 64 + lane];
        A0.x = fmaf(w0, v0.x, A0.x); A0.y = fmaf(w0, v0.y, A0.y);
        A0.z = fmaf(w0, v0.z, A0.z); A0.w = fmaf(w0, v0.w, A0.w);
        A1.x = fmaf(w1, v1.x, A1.x); A1.y = fmaf(w1, v1.y, A1.y);
        A1.z = fmaf(w1, v1.z, A1.z); A1.w = fmaf(w1, v1.w, A1.w);
        A2.x = fmaf(w2, v2.x, A2.x); A2.y = fmaf(w2, v2.y, A2.y);
        A2.z = fmaf(w2, v2.z, A2.z); A2.w = fmaf(w2, v2.w, A2.w);
        A3.x = fmaf(w3, v3.x, A3.x); A3.y = fmaf(w3, v3.y, A3.y);
        A3.z = fmaf(w3, v3.z, A3.z); A3.w = fmaf(w3, v3.w, A3.w);
        A0.x = fmaf(w4, v4.x, A0.x); A0.y = fmaf(w4, v4.y, A0.y);
        A0.z = fmaf(w4, v4.z, A0.z); A0.w = fmaf(w4, v4.w, A0.w);
        A1.x = fmaf(w5, v5.x, A1.x); A1.y = fmaf(w5, v5.y, A1.y);
        A1.z = fmaf(w5, v5.z, A1.z); A1.w = fmaf(w5, v5.w, A1.w);
        A2.x = fmaf(w6, v6.x, A2.x); A2.y = fmaf(w6, v6.y, A2.y);
        A2.z = fmaf(w6, v6.z, A2.z); A2.w = fmaf(w6, v6.w, A2.w);
        A3.x = fmaf(w7, v7.x, A3.x); A3.y = fmaf(w7, v7.y, A3.y);
        A3.z = fmaf(w7, v7.z, A3.z); A3.w = fmaf(w7, v7.w, A3.w);
    }
    for (; j < r1; ++j) {
        const int s0 = psrc[j];
        const float w0 = elw(a_s[s0 * NH + hh] + ad);
        sum += w0;
        const float4 v0 = X4[(size_t)s0 * 64 + lane];
        A0.x = fmaf(w0, v0.x, A0.x); A0.y = fmaf(w0, v0.y, A0.y);
        A0.z = fmaf(w0, v0.z, A0.z); A0.w = fmaf(w0, v0.w, A0.w);
    }
    const float inv = 1.f / (sum + 1e-30f);
    float4 t;
    t.x = ((A0.x + A1.x) + (A2.x + A3.x)) * inv;
    t.y = ((A0.y + A1.y) + (A2.y + A3.y)) * inv;
    t.z = ((A0.z + A1.z) + (A2.z + A3.z)) * inv;
    t.w = ((A0.w + A1.w) + (A2.w + A3.w)) * inv;
    #pragma unroll
    for (int msk = 16; msk < 64; msk <<= 1) {
        t.x += __shfl_xor(t.x, msk, 64);
        t.y += __shfl_xor(t.y, msk, 64);
        t.z += __shfl_xor(t.z, msk, 64);
        t.w += __shfl_xor(t.w, msk, 64);
    }
    if (lane < 16) {
        const float4 b = ((const float4*)bias)[lane];
        float4 o;
        o.x = t.x * 0.25f + b.x; o.y = t.y * 0.25f + b.y;
        o.z = t.z * 0.25f + b.z; o.w = t.w * 0.25f + b.w;
        ((float4*)out)[(size_t)n * 16 + lane] = o;
    }
}

// ---------- Layer 2: SINGLE-PASS softmax+aggregate, HC=128, half-wave per edge ----------
// Stores RAW w per edge-head into alpha_p and 1/sum per (node,head) into inv_s;
// edge_mlp applies the normalization (same product/rounding as storing normalized).
__global__ __launch_bounds__(256) void softagg2(const int* __restrict__ rowptr,
                                                const int* __restrict__ psrc,
                                                const float* __restrict__ a_s,
                                                const float* __restrict__ a_d,
                                                float* __restrict__ alpha_p,
                                                float* __restrict__ inv_s,
                                                const float* __restrict__ xl,
                                                const float* __restrict__ bias,
                                                float* __restrict__ out) {
    const int wv = threadIdx.x >> 6, lane = threadIdx.x & 63;
    const int n = blockIdx.x * 4 + wv;
    if (n >= NN) return;
    const int r0 = rowptr[n], r1 = rowptr[n + 1];
    const int cl = lane & 31, half = lane >> 5, hh = cl >> 3;
    const float ad = a_d[n * NH + hh];
    const bool writer = (cl & 7) == 0;   // one lane per (half, head) writes raw w

    const float4* X4 = (const float4*)xl;   // row stride 32 float4
    float4 A0 = {0,0,0,0}, A1 = {0,0,0,0};
    float sum = 0.f;
    int j = r0;
    for (; j + 7 < r1; j += 8) {
        const int ja = j + half, jc = j + 2 + half, je = j + 4 + half, jg = j + 6 + half;
        const int sa = psrc[ja], sc = psrc[jc], se = psrc[je], sg = psrc[jg];
        const float wa = elw(a_s[sa * NH + hh] + ad);
        const float wc = elw(a_s[sc * NH + hh] + ad);
        const float we = elw(a_s[se * NH + hh] + ad);
        const float wg = elw(a_s[sg * NH + hh] + ad);
        if (writer) {
            alpha_p[ja * NH + hh] = wa; alpha_p[jc * NH + hh] = wc;
            alpha_p[je * NH + hh] = we; alpha_p[jg * NH + hh] = wg;
        }
        sum += (wa + wc) + (we + wg);
        const float4 va = X4[(size_t)sa * 32 + cl];
        const float4 vc = X4[(size_t)sc * 32 + cl];
        const float4 ve = X4[(size_t)se * 32 + cl];
        const float4 vg = X4[(size_t)sg * 32 + cl];
        A0.x = fmaf(wa, va.x, A0.x); A0.y = fmaf(wa, va.y, A0.y);
        A0.z = fmaf(wa, va.z, A0.z); A0.w = fmaf(wa, va.w, A0.w);
        A1.x = fmaf(wc, vc.x, A1.x); A1.y = fmaf(wc, vc.y, A1.y);
        A1.z = fmaf(wc, vc.z, A1.z); A1.w = fmaf(wc, vc.w, A1.w);
        A0.x = fmaf(we, ve.x, A0.x); A0.y = fmaf(we, ve.y, A0.y);
        A0.z = fmaf(we, ve.z, A0.z); A0.w = fmaf(we, ve.w, A0.w);
        A1.x = fmaf(wg, vg.x, A1.x); A1.y = fmaf(wg, vg.y, A1.y);
        A1.z = fmaf(wg, vg.z, A1.z); A1.w = fmaf(wg, vg.w, A1.w);
    }
    for (; j < r1; j += 2) {
        const int ja = j + half;
        const bool valid = ja < r1;
        const int sa = psrc[valid ? ja : r0];
        float wa = 0.f;
        if (valid) {
            wa = elw(a_s[sa * NH + hh] + ad);
            if (writer) alpha_p[ja * NH + hh] = wa;
        }
        sum += wa;
        const float4 va = X4[(size_t)sa * 32 + cl];
        A0.x = fmaf(wa, va.x, A0.x); A0.y = fmaf(wa, va.y, A0.y);
        A0.z = fmaf(wa, va.z, A0.z); A0.w = fmaf(wa, va.w, A0.w);
    }
    // merge halves' partial sums, then normalize
    sum += __shfl_xor(sum, 32, 64);
    const float inv = 1.f / (sum + 1e-30f);
    if (writer && half == 0) inv_s[n * NH + hh] = inv;

    float4 t;
    t.x = A0.x + A1.x; t.y = A0.y + A1.y; t.z = A0.z + A1.z; t.w = A0.w + A1.w;
    t.x += __shfl_xor(t.x, 32, 64);
    t.y += __shfl_xor(t.y, 32, 64);
    t.z += __shfl_xor(t.z, 32, 64);
    t.w += __shfl_xor(t.w, 32, 64);
    t.x *= inv; t.y *= inv; t.z *= inv; t.w *= inv;
    #pragma unroll
    for (int q = 0; q < 2; ++q) {
        const int msk = (q == 0) ? 8 : 16;
        t.x += __shfl_xor(t.x, msk, 64);
        t.y += __shfl_xor(t.y, msk, 64);
        t.z += __shfl_xor(t.z, msk, 64);
        t.w += __shfl_xor(t.w, msk, 64);
    }
    if (lane < 8) {
        const float4 b = ((const float4*)bias)[lane];
        float4 o;
        o.x = t.x * 0.25f + b.x; o.y = t.y * 0.25f + b.y;
        o.z = t.z * 0.25f + b.z; o.w = t.w * 0.25f + b.w;
        ((float4*)out)[(size_t)n * 8 + lane] = o;
    }
}

// ---------- pack W1 src/dst row-blocks into [32][128] for the PQ GEMM ----------
__global__ __launch_bounds__(256) void pack_w1(const float* __restrict__ mW1,
                                               float* __restrict__ W1pq) {
    const int idx = blockIdx.x * 256 + threadIdx.x;   // 32*128 = 4096
    if (idx >= 32 * 128) return;
    const int k = idx >> 7, j = idx & 127;
    W1pq[idx] = (j < 64) ? mW1[k * 64 + j] : mW1[(36 + k) * 64 + (j - 64)];
}

// ---------- factored edge MLP v2: 4 edges per wave, 16 lanes (x float4 hid) per edge ----
// alpha_p now holds RAW w; normalization via inv_s[dst] (broadcast, CSR-local → L1 hit).
__global__ __launch_bounds__(256) void edge_mlp_fast2(const float* __restrict__ PQ,      // [N,128]
                                                      const float* __restrict__ alpha_p, // [E,4] CSR raw w
                                                      const float* __restrict__ inv_s,   // [N,4]
                                                      const int* __restrict__ psrc,
                                                      const int* __restrict__ pdst,
                                                      const int* __restrict__ perm,
                                                      const float* __restrict__ mW1,     // rows 32..35
                                                      const float* __restrict__ mb1,
                                                      const float* __restrict__ mW2,
                                                      const float* __restrict__ mb2,
                                                      float* __restrict__ out) {         // [E,2]
    const int lane = threadIdx.x & 63, wv = threadIdx.x >> 6;
    const int g = lane >> 4, c = lane & 15;

    const float4 wa0 = *(const float4*)&mW1[32 * 64 + c * 4];
    const float4 wa1 = *(const float4*)&mW1[33 * 64 + c * 4];
    const float4 wa2 = *(const float4*)&mW1[34 * 64 + c * 4];
    const float4 wa3 = *(const float4*)&mW1[35 * 64 + c * 4];
    const float4 b1v = *(const float4*)&mb1[c * 4];
    const float4 w2a = *(const float4*)&mW2[c * 8];
    const float4 w2b = *(const float4*)&mW2[c * 8 + 4];
    const float bo0 = mb2[0], bo1 = mb2[1];

    const float4* PQ4 = (const float4*)PQ;   // row stride 32 float4
    const int gw = blockIdx.x * 4 + wv;
    const int stride4 = gridDim.x * 4 * 4;

    for (int jb = gw * 4; jb < EE; jb += stride4) {
        const int j = jb + g;
        const int s = psrc[j];
        const int d = pdst[j];
        const float4 ar = *(const float4*)&alpha_p[(size_t)j * 4];
        const float4 iv = *(const float4*)&inv_s[(size_t)d * 4];
        const float al0 = ar.x * iv.x, al1 = ar.y * iv.y;
        const float al2 = ar.z * iv.z, al3 = ar.w * iv.w;
        const float4 p = PQ4[(size_t)s * 32 + c];
        const float4 q = PQ4[(size_t)d * 32 + 16 + c];
        float4 h;
        h.x = p.x + q.x + b1v.x; h.y = p.y + q.y + b1v.y;
        h.z = p.z + q.z + b1v.z; h.w = p.w + q.w + b1v.w;
        h.x = fmaf(al0, wa0.x, h.x); h.y = fmaf(al0, wa0.y, h.y);
        h.z = fmaf(al0, wa0.z, h.z); h.w = fmaf(al0, wa0.w, h.w);
        h.x = fmaf(al1, wa1.x, h.x); h.y = fmaf(al1, wa1.y, h.y);
        h.z = fmaf(al1, wa1.z, h.z); h.w = fmaf(al1, wa1.w, h.w);
        h.x = fmaf(al2, wa2.x, h.x); h.y = fmaf(al2, wa2.y, h.y);
        h.z = fmaf(al2, wa2.z, h.z); h.w = fmaf(al2, wa2.w, h.w);
        h.x = fmaf(al3, wa3.x, h.x); h.y = fmaf(al3, wa3.y, h.y);
        h.z = fmaf(al3, wa3.z, h.z); h.w = fmaf(al3, wa3.w, h.w);
        h.x = fmaxf(h.x, 0.f); h.y = fmaxf(h.y, 0.f);
        h.z = fmaxf(h.z, 0.f); h.w = fmaxf(h.w, 0.f);

        float v0 = h.x * w2a.x + h.y * w2a.z + h.z * w2b.x + h.w * w2b.z;
        float v1 = h.x * w2a.y + h.y * w2a.w + h.z * w2b.y + h.w * w2b.w;
        #pragma unroll
        for (int msk = 1; msk < 16; msk <<= 1) {
            v0 += __shfl_xor(v0, msk, 64);
            v1 += __shfl_xor(v1, msk, 64);
        }
        if (c == 0)
            *(float2*)&out[(size_t)perm[j] * 2] = make_float2(v0 + bo0, v1 + bo1);
    }
}

extern "C" void kernel_launch(void* const* d_in, const int* in_sizes, int n_in,
                              void* d_out, int out_size, void* d_ws, size_t ws_size,
                              hipStream_t stream) {
    const float* x        = (const float*)d_in[0];
    const int*   ei       = (const int*)d_in[1];
    // d_in[2] edge_attr: unused (edge_dim=None). d_in[3] flag: unused.
    const float* W1       = (const float*)d_in[4];
    const float* att1_src = (const float*)d_in[5];
    const float* att1_dst = (const float*)d_in[6];
    const float* b1       = (const float*)d_in[7];
    const float* W3       = (const float*)d_in[8];
    const float* att3_src = (const float*)d_in[9];
    const float* att3_dst = (const float*)d_in[10];
    const float* b3       = (const float*)d_in[11];
    const float* mW1      = (const float*)d_in[12];
    const float* mb1      = (const float*)d_in[13];
    const float* mW2      = (const float*)d_in[14];
    const float* mb2      = (const float*)d_in[15];

    float* out_nodes = (float*)d_out;               // [N,32]
    float* out_edges = out_nodes + (size_t)NN * 32; // [E,2]

    // workspace layout (floats/ints)
    float* ws = (float*)d_ws;
    float*    xl      = ws;                           // N*256 = 12.8M (layer GEMM out)
    float*    PQ      = ws;                           // N*128, written AFTER xl's last use
    float*    h1      = ws + 12800000;                // N*64
    float*    alpha_p = ws + 16000000;                // E*4 (CSR-order raw w, layer 2)
    float*    a_s     = ws + 25600000;                // N*4
    float*    a_d     = ws + 25800000;                // N*4
    float*    W1pq    = ws + 26000000;                // 32*128
    float*    inv_s   = ws + 26100000;                // N*4  (1/softmax-denominator, layer 2)
    int*      deg     = (int*)(ws + 26400000);        // N
    int*      cursor  = (int*)(ws + 26450000);        // N
    int*      rowptr  = (int*)(ws + 26500000);        // N+1
    int*      perm    = (int*)(ws + 26550008);        // E
    int*      psrc    = (int*)(ws + 27350008);        // E
    int*      pdst    = (int*)(ws + 28150008);        // E

    const int gemmRows = (NN + 63) / 64;  // 782
    const int EB = (EE + 255) / 256;      // 3125
    const int NB4 = (NN + 3) / 4;         // wave-per-node blocks (4 waves/block)

    // ======== CSR build (shared by both layers) ========
    hipMemsetAsync(deg, 0, (size_t)NN * 4, stream);
    count_deg_k<<<EB, 256, 0, stream>>>(ei, deg);
    scan_k<<<1, 1024, 0, stream>>>(deg, rowptr, cursor);
    scatter_perm_k<<<EB, 256, 0, stream>>>(ei, cursor, perm, psrc, pdst);
    pack_w1<<<16, 256, 0, stream>>>(mW1, W1pq);

    // ======== Layer 1 (C=64, HC=256) ========
    gemm_att<64><<<dim3(gemmRows, 4), 256, 0, stream>>>(x, W1, xl, att1_src, att1_dst,
                                                        a_s, a_d, NN, INF, NH * 64);
    softagg1<<<NB4, 256, 0, stream>>>(rowptr, psrc, a_s, a_d, xl, b1, h1);

    // ======== Layer 2 (C=32, HC=128) ========
    gemm_att<32><<<dim3(gemmRows, 2), 256, 0, stream>>>(h1, W3, xl, att3_src, att3_dst,
                                                        a_s, a_d, NN, 64, NH * 32);
    softagg2<<<NB4, 256, 0, stream>>>(rowptr, psrc, a_s, a_d, alpha_p, inv_s, xl, b3,
                                      out_nodes);

    // ======== Edge MLP (factored): PQ = out_nodes @ [W1[0:32] | W1[36:68]] ========
    // xl is dead after softagg2 -> reuse its region for PQ.
    gemm_tiled<<<dim3(gemmRows, 2), 256, 0, stream>>>(out_nodes, W1pq, PQ, NN, 32, 128);
    edge_mlp_fast2<<<2048, 256, 0, stream>>>(PQ, alpha_p, inv_s, psrc, pdst, perm,
                                             mW1, mb1, mW2, mb2, out_edges);
}

// Round 2
// 504.508 us; speedup vs baseline: 1.1275x; 1.0852x over previous
//
#include <hip/hip_runtime.h>
#include <hip/hip_fp16.h>

// Problem constants
constexpr int NN   = 50000;
constexpr int EE   = 800000;
constexpr int INF  = 128;   // input feat
constexpr int NH   = 4;     // heads

struct __align__(8) h4 { __half2 a, b; };   // 4 halves = 8 bytes

__device__ __forceinline__ float elw(float a) {
    a = (a > 0.f) ? a : 0.2f * a;          // leaky_relu(0.2)
    return __expf(a);                       // exp without max-sub (scores bounded)
}

// ---------- Tiled fp32 GEMM (64x64, 4x4) with fp16 output: PQ GEMM ----------
__global__ __launch_bounds__(256) void gemm_pq_half(const float* __restrict__ A,
                                                    const float* __restrict__ B,
                                                    __half* __restrict__ C,
                                                    int N, int K, int M) {
    __shared__ float As[16][68];   // [k][row], padded
    __shared__ float Bs[16][64];   // [k][col]
    const int tid = threadIdx.x;
    const int tx = tid & 15, ty = tid >> 4;
    const int row0 = blockIdx.x * 64, col0 = blockIdx.y * 64;

    float acc[4][4] = {};

    for (int k0 = 0; k0 < K; k0 += 16) {
        {
            const int a_row = tid >> 2;
            const int a_k   = (tid & 3) * 4;
            const int gr    = row0 + a_row;
            float4 v = make_float4(0.f, 0.f, 0.f, 0.f);
            if (gr < N) v = *(const float4*)(A + (size_t)gr * K + k0 + a_k);
            As[a_k + 0][a_row] = v.x;
            As[a_k + 1][a_row] = v.y;
            As[a_k + 2][a_row] = v.z;
            As[a_k + 3][a_row] = v.w;
        }
        {
            const int b_k = tid >> 4;
            const int b_c = (tid & 15) * 4;
            float4 w = *(const float4*)(B + (size_t)(k0 + b_k) * M + col0 + b_c);
            *(float4*)&Bs[b_k][b_c] = w;
        }
        __syncthreads();
        #pragma unroll
        for (int kk = 0; kk < 16; ++kk) {
            float4 a = *(const float4*)&As[kk][ty * 4];
            float4 b = *(const float4*)&Bs[kk][tx * 4];
            const float av[4] = {a.x, a.y, a.z, a.w};
            const float bv[4] = {b.x, b.y, b.z, b.w};
            #pragma unroll
            for (int i = 0; i < 4; ++i)
                #pragma unroll
                for (int j = 0; j < 4; ++j)
                    acc[i][j] = fmaf(av[i], bv[j], acc[i][j]);
        }
        __syncthreads();
    }
    #pragma unroll
    for (int i = 0; i < 4; ++i) {
        const int r = row0 + ty * 4 + i;
        if (r < N) {
            __half* cp = C + (size_t)r * M + col0 + tx * 4;
            __half2 q0 = __halves2half2(__float2half_rn(acc[i][0]), __float2half_rn(acc[i][1]));
            __half2 q1 = __halves2half2(__float2half_rn(acc[i][2]), __float2half_rn(acc[i][3]));
            *(__half2*)cp       = q0;
            *(__half2*)(cp + 2) = q1;
        }
    }
}

// ---------- Tiled fp32 GEMM (64-tile) with fused attention-score epilogue ----------
// HOUT: store C as fp16 (layer-1 xl). Attention scores always computed from fp32 acc.
template <int CH, bool HOUT>
__global__ __launch_bounds__(256) void gemm_att(const float* __restrict__ A,
                                                const float* __restrict__ B,
                                                void* __restrict__ Cv,
                                                const float* __restrict__ att_s,
                                                const float* __restrict__ att_d,
                                                float* __restrict__ a_s,
                                                float* __restrict__ a_d,
                                                int N, int K, int M) {
    __shared__ float As[16][68];   // [k][row], padded
    __shared__ float Bs[16][64];   // [k][col]
    const int tid = threadIdx.x;
    const int tx = tid & 15, ty = tid >> 4;
    const int row0 = blockIdx.x * 64, col0 = blockIdx.y * 64;

    const int col  = col0 + tx * 4;
    const int head = col / CH;
    const int pos  = col % CH;
    float attS[4], attD[4];
    #pragma unroll
    for (int j = 0; j < 4; ++j) {
        attS[j] = att_s[head * CH + pos + j];
        attD[j] = att_d[head * CH + pos + j];
    }

    float acc[4][4] = {};

    for (int k0 = 0; k0 < K; k0 += 16) {
        {
            const int a_row = tid >> 2;
            const int a_k   = (tid & 3) * 4;
            const int gr    = row0 + a_row;
            float4 v = make_float4(0.f, 0.f, 0.f, 0.f);
            if (gr < N) v = *(const float4*)(A + (size_t)gr * K + k0 + a_k);
            As[a_k + 0][a_row] = v.x;
            As[a_k + 1][a_row] = v.y;
            As[a_k + 2][a_row] = v.z;
            As[a_k + 3][a_row] = v.w;
        }
        {
            const int b_k = tid >> 4;
            const int b_c = (tid & 15) * 4;
            float4 w = *(const float4*)(B + (size_t)(k0 + b_k) * M + col0 + b_c);
            *(float4*)&Bs[b_k][b_c] = w;
        }
        __syncthreads();
        #pragma unroll
        for (int kk = 0; kk < 16; ++kk) {
            float4 a = *(const float4*)&As[kk][ty * 4];
            float4 b = *(const float4*)&Bs[kk][tx * 4];
            const float av[4] = {a.x, a.y, a.z, a.w};
            const float bv[4] = {b.x, b.y, b.z, b.w};
            #pragma unroll
            for (int i = 0; i < 4; ++i)
                #pragma unroll
                for (int j = 0; j < 4; ++j)
                    acc[i][j] = fmaf(av[i], bv[j], acc[i][j]);
        }
        __syncthreads();
    }
    #pragma unroll
    for (int i = 0; i < 4; ++i) {
        const int r = row0 + ty * 4 + i;
        if (r < N) {
            if constexpr (HOUT) {
                __half* C  = (__half*)Cv;
                __half* cp = C + (size_t)r * M + col0 + tx * 4;
                __half2 q0 = __halves2half2(__float2half_rn(acc[i][0]), __float2half_rn(acc[i][1]));
                __half2 q1 = __halves2half2(__float2half_rn(acc[i][2]), __float2half_rn(acc[i][3]));
                *(__half2*)cp       = q0;
                *(__half2*)(cp + 2) = q1;
            } else {
                float* C  = (float*)Cv;
                float* cp = C + (size_t)r * M + col0 + tx * 4;
                cp[0] = acc[i][0]; cp[1] = acc[i][1]; cp[2] = acc[i][2]; cp[3] = acc[i][3];
            }
        }
        float ss = 0.f, sd = 0.f;
        #pragma unroll
        for (int j = 0; j < 4; ++j) {
            ss = fmaf(acc[i][j], attS[j], ss);
            sd = fmaf(acc[i][j], attD[j], sd);
        }
        #pragma unroll
        for (int msk = 1; msk < CH / 4; msk <<= 1) {
            ss += __shfl_xor(ss, msk, 64);
            sd += __shfl_xor(sd, msk, 64);
        }
        if ((tx & (CH / 4 - 1)) == 0 && r < N) {
            a_s[r * NH + head] = ss;
            a_d[r * NH + head] = sd;
        }
    }
}

// ---------- CSR build ----------
__global__ __launch_bounds__(256) void count_deg_k(const int* __restrict__ ei,
                                                   int* __restrict__ deg) {
    const int e = blockIdx.x * 256 + threadIdx.x;
    if (e < EE) atomicAdd(&deg[ei[EE + e]], 1);
}

// single-block exclusive scan over deg[0..NN) -> rowptr[0..NN], cursor copy
__global__ __launch_bounds__(1024) void scan_k(const int* __restrict__ deg,
                                               int* __restrict__ rowptr,
                                               int* __restrict__ cursor) {
    __shared__ int wsum[16];
    const int tid = threadIdx.x;
    const int lane = tid & 63, wv = tid >> 6;
    int total = 0;
    for (int base = 0; base < NN; base += 1024) {
        const int i = base + tid;
        const int v = (i < NN) ? deg[i] : 0;
        int incl = v;
        #pragma unroll
        for (int d = 1; d < 64; d <<= 1) {
            int t = __shfl_up(incl, d, 64);
            if (lane >= d) incl += t;
        }
        if (lane == 63) wsum[wv] = incl;
        __syncthreads();
        if (wv == 0) {
            int s = (lane < 16) ? wsum[lane] : 0;
            #pragma unroll
            for (int d = 1; d < 16; d <<= 1) {
                int t = __shfl_up(s, d, 64);
                if (lane >= d) s += t;
            }
            if (lane < 16) wsum[lane] = s;
        }
        __syncthreads();
        const int excl = total + (wv > 0 ? wsum[wv - 1] : 0) + incl - v;
        const int chunk = wsum[15];
        if (i < NN) { rowptr[i] = excl; cursor[i] = excl; }
        total += chunk;
        __syncthreads();   // protect wsum before next iteration's writes
    }
    if (tid == 0) rowptr[NN] = total;
}

__global__ __launch_bounds__(256) void scatter_perm_k(const int* __restrict__ ei,
                                                      int* __restrict__ cursor,
                                                      int* __restrict__ perm,
                                                      int* __restrict__ psrc,
                                                      int* __restrict__ pdst) {
    const int e = blockIdx.x * 256 + threadIdx.x;
    if (e >= EE) return;
    const int d = ei[EE + e];
    const int p = atomicAdd(&cursor[d], 1);
    perm[p] = e;
    psrc[p] = ei[e];
    pdst[p] = d;
}

// ---------- Layer 1: SINGLE-PASS softmax+aggregate, fp16 xl payload, HC=256 ----------
// One wave per dst node; lane owns 4 channels (8 B/lane/edge instead of 16 B).
__global__ __launch_bounds__(256) void softagg1h(const int* __restrict__ rowptr,
                                                 const int* __restrict__ psrc,
                                                 const float* __restrict__ a_s,
                                                 const float* __restrict__ a_d,
                                                 const __half* __restrict__ xl,
                                                 const float* __restrict__ bias,
                                                 float* __restrict__ out) {
    const int wv = threadIdx.x >> 6, lane = threadIdx.x & 63;
    const int n = blockIdx.x * 4 + wv;
    if (n >= NN) return;
    const int r0 = rowptr[n], r1 = rowptr[n + 1];
    const int hh = lane >> 4;
    const float ad = a_d[n * NH + hh];

    const h4* X = (const h4*)xl;   // row stride 64 h4 units (256 halves)
    float4 A0 = {0,0,0,0}, A1 = {0,0,0,0}, A2 = {0,0,0,0}, A3 = {0,0,0,0};
    float sum = 0.f;
    int j = r0;
    for (; j + 7 < r1; j += 8) {
        const int s0 = psrc[j],     s1 = psrc[j + 1], s2 = psrc[j + 2], s3 = psrc[j + 3];
        const int s4 = psrc[j + 4], s5 = psrc[j + 5], s6 = psrc[j + 6], s7 = psrc[j + 7];
        const float w0 = elw(a_s[s0 * NH + hh] + ad);
        const float w1 = elw(a_s[s1 * NH + hh] + ad);
        const float w2 = elw(a_s[s2 * NH + hh] + ad);
        const float w3 = elw(a_s[s3 * NH + hh] + ad);
        const float w4 = elw(a_s[s4 * NH + hh] + ad);
        const float w5 = elw(a_s[s5 * NH + hh] + ad);
        const float w6 = elw(a_s[s6 * NH + hh] + ad);
        const float w7 = elw(a_s[s7 * NH + hh] + ad);
        sum += ((w0 + w1) + (w2 + w3)) + ((w4 + w5) + (w6 + w7));
        const h4 v0 = X[(size_t)s0 * 64 + lane];
        const h4 v1 = X[(size_t)s1 * 64 + lane];
        const h4 v2 = X[(size_t)s2 * 64 + lane];
        const h4 v3 = X[(size_t)s3 * 64 + lane];
        const h4 v4 = X[(size_t)s4 * 64 + lane];
        const h4 v5 = X[(size_t)s5 * 64 + lane];
        const h4 v6 = X[(size_t)s6 * 64 + lane];
        const h4 v7 = X[(size_t)s7 * 64 + lane];
        float2 l0 = __half22float2(v0.a), m0 = __half22float2(v0.b);
        float2 l1 = __half22float2(v1.a), m1 = __half22float2(v1.b);
        float2 l2 = __half22float2(v2.a), m2 = __half22float2(v2.b);
        float2 l3 = __half22float2(v3.a), m3 = __half22float2(v3.b);
        float2 l4 = __half22float2(v4.a), m4 = __half22float2(v4.b);
        float2 l5 = __half22float2(v5.a), m5 = __half22float2(v5.b);
        float2 l6 = __half22float2(v6.a), m6 = __half22float2(v6.b);
        float2 l7 = __half22float2(v7.a), m7 = __half22float2(v7.b);
        A0.x = fmaf(w0, l0.x, A0.x); A0.y = fmaf(w0, l0.y, A0.y);
        A0.z = fmaf(w0, m0.x, A0.z); A0.w = fmaf(w0, m0.y, A0.w);
        A1.x = fmaf(w1, l1.x, A1.x); A1.y = fmaf(w1, l1.y, A1.y);
        A1.z = fmaf(w1, m1.x, A1.z); A1.w = fmaf(w1, m1.y, A1.w);
        A2.x = fmaf(w2, l2.x, A2.x); A2.y = fmaf(w2, l2.y, A2.y);
        A2.z = fmaf(w2, m2.x, A2.z); A2.w = fmaf(w2, m2.y, A2.w);
        A3.x = fmaf(w3, l3.x, A3.x); A3.y = fmaf(w3, l3.y, A3.y);
        A3.z = fmaf(w3, m3.x, A3.z); A3.w = fmaf(w3, m3.y, A3.w);
        A0.x = fmaf(w4, l4.x, A0.x); A0.y = fmaf(w4, l4.y, A0.y);
        A0.z = fmaf(w4, m4.x, A0.z); A0.w = fmaf(w4, m4.y, A0.w);
        A1.x = fmaf(w5, l5.x, A1.x); A1.y = fmaf(w5, l5.y, A1.y);
        A1.z = fmaf(w5, m5.x, A1.z); A1.w = fmaf(w5, m5.y, A1.w);
        A2.x = fmaf(w6, l6.x, A2.x); A2.y = fmaf(w6, l6.y, A2.y);
        A2.z = fmaf(w6, m6.x, A2.z); A2.w = fmaf(w6, m6.y, A2.w);
        A3.x = fmaf(w7, l7.x, A3.x); A3.y = fmaf(w7, l7.y, A3.y);
        A3.z = fmaf(w7, m7.x, A3.z); A3.w = fmaf(w7, m7.y, A3.w);
    }
    for (; j < r1; ++j) {
        const int s0 = psrc[j];
        const float w0 = elw(a_s[s0 * NH + hh] + ad);
        sum += w0;
        const h4 v0 = X[(size_t)s0 * 64 + lane];
        float2 l0 = __half22float2(v0.a), m0 = __half22float2(v0.b);
        A0.x = fmaf(w0, l0.x, A0.x); A0.y = fmaf(w0, l0.y, A0.y);
        A0.z = fmaf(w0, m0.x, A0.z); A0.w = fmaf(w0, m0.y, A0.w);
    }
    const float inv = 1.f / (sum + 1e-30f);
    float4 t;
    t.x = ((A0.x + A1.x) + (A2.x + A3.x)) * inv;
    t.y = ((A0.y + A1.y) + (A2.y + A3.y)) * inv;
    t.z = ((A0.z + A1.z) + (A2.z + A3.z)) * inv;
    t.w = ((A0.w + A1.w) + (A2.w + A3.w)) * inv;
    #pragma unroll
    for (int msk = 16; msk < 64; msk <<= 1) {
        t.x += __shfl_xor(t.x, msk, 64);
        t.y += __shfl_xor(t.y, msk, 64);
        t.z += __shfl_xor(t.z, msk, 64);
        t.w += __shfl_xor(t.w, msk, 64);
    }
    if (lane < 16) {
        const float4 b = ((const float4*)bias)[lane];
        float4 o;
        o.x = t.x * 0.25f + b.x; o.y = t.y * 0.25f + b.y;
        o.z = t.z * 0.25f + b.z; o.w = t.w * 0.25f + b.w;
        ((float4*)out)[(size_t)n * 16 + lane] = o;
    }
}

// ---------- Layer 2: SINGLE-PASS softmax+aggregate, HC=128 (fp32, feeds final outs) ----------
__global__ __launch_bounds__(256) void softagg2(const int* __restrict__ rowptr,
                                                const int* __restrict__ psrc,
                                                const float* __restrict__ a_s,
                                                const float* __restrict__ a_d,
                                                float* __restrict__ alpha_p,
                                                float* __restrict__ inv_s,
                                                const float* __restrict__ xl,
                                                const float* __restrict__ bias,
                                                float* __restrict__ out) {
    const int wv = threadIdx.x >> 6, lane = threadIdx.x & 63;
    const int n = blockIdx.x * 4 + wv;
    if (n >= NN) return;
    const int r0 = rowptr[n], r1 = rowptr[n + 1];
    const int cl = lane & 31, half = lane >> 5, hh = cl >> 3;
    const float ad = a_d[n * NH + hh];
    const bool writer = (cl & 7) == 0;   // one lane per (half, head) writes raw w

    const float4* X4 = (const float4*)xl;   // row stride 32 float4
    float4 A0 = {0,0,0,0}, A1 = {0,0,0,0};
    float sum = 0.f;
    int j = r0;
    for (; j + 7 < r1; j += 8) {
        const int ja = j + half, jc = j + 2 + half, je = j + 4 + half, jg = j + 6 + half;
        const int sa = psrc[ja], sc = psrc[jc], se = psrc[je], sg = psrc[jg];
        const float wa = elw(a_s[sa * NH + hh] + ad);
        const float wc = elw(a_s[sc * NH + hh] + ad);
        const float we = elw(a_s[se * NH + hh] + ad);
        const float wg = elw(a_s[sg * NH + hh] + ad);
        if (writer) {
            alpha_p[ja * NH + hh] = wa; alpha_p[jc * NH + hh] = wc;
            alpha_p[je * NH + hh] = we; alpha_p[jg * NH + hh] = wg;
        }
        sum += (wa + wc) + (we + wg);
        const float4 va = X4[(size_t)sa * 32 + cl];
        const float4 vc = X4[(size_t)sc * 32 + cl];
        const float4 ve = X4[(size_t)se * 32 + cl];
        const float4 vg = X4[(size_t)sg * 32 + cl];
        A0.x = fmaf(wa, va.x, A0.x); A0.y = fmaf(wa, va.y, A0.y);
        A0.z = fmaf(wa, va.z, A0.z); A0.w = fmaf(wa, va.w, A0.w);
        A1.x = fmaf(wc, vc.x, A1.x); A1.y = fmaf(wc, vc.y, A1.y);
        A1.z = fmaf(wc, vc.z, A1.z); A1.w = fmaf(wc, vc.w, A1.w);
        A0.x = fmaf(we, ve.x, A0.x); A0.y = fmaf(we, ve.y, A0.y);
        A0.z = fmaf(we, ve.z, A0.z); A0.w = fmaf(we, ve.w, A0.w);
        A1.x = fmaf(wg, vg.x, A1.x); A1.y = fmaf(wg, vg.y, A1.y);
        A1.z = fmaf(wg, vg.z, A1.z); A1.w = fmaf(wg, vg.w, A1.w);
    }
    for (; j < r1; j += 2) {
        const int ja = j + half;
        const bool valid = ja < r1;
        const int sa = psrc[valid ? ja : r0];
        float wa = 0.f;
        if (valid) {
            wa = elw(a_s[sa * NH + hh] + ad);
            if (writer) alpha_p[ja * NH + hh] = wa;
        }
        sum += wa;
        const float4 va = X4[(size_t)sa * 32 + cl];
        A0.x = fmaf(wa, va.x, A0.x); A0.y = fmaf(wa, va.y, A0.y);
        A0.z = fmaf(wa, va.z, A0.z); A0.w = fmaf(wa, va.w, A0.w);
    }
    // merge halves' partial sums, then normalize
    sum += __shfl_xor(sum, 32, 64);
    const float inv = 1.f / (sum + 1e-30f);
    if (writer && half == 0) inv_s[n * NH + hh] = inv;

    float4 t;
    t.x = A0.x + A1.x; t.y = A0.y + A1.y; t.z = A0.z + A1.z; t.w = A0.w + A1.w;
    t.x += __shfl_xor(t.x, 32, 64);
    t.y += __shfl_xor(t.y, 32, 64);
    t.z += __shfl_xor(t.z, 32, 64);
    t.w += __shfl_xor(t.w, 32, 64);
    t.x *= inv; t.y *= inv; t.z *= inv; t.w *= inv;
    #pragma unroll
    for (int q = 0; q < 2; ++q) {
        const int msk = (q == 0) ? 8 : 16;
        t.x += __shfl_xor(t.x, msk, 64);
        t.y += __shfl_xor(t.y, msk, 64);
        t.z += __shfl_xor(t.z, msk, 64);
        t.w += __shfl_xor(t.w, msk, 64);
    }
    if (lane < 8) {
        const float4 b = ((const float4*)bias)[lane];
        float4 o;
        o.x = t.x * 0.25f + b.x; o.y = t.y * 0.25f + b.y;
        o.z = t.z * 0.25f + b.z; o.w = t.w * 0.25f + b.w;
        ((float4*)out)[(size_t)n * 8 + lane] = o;
    }
}

// ---------- pack W1 src/dst row-blocks into [32][128] for the PQ GEMM ----------
__global__ __launch_bounds__(256) void pack_w1(const float* __restrict__ mW1,
                                               float* __restrict__ W1pq) {
    const int idx = blockIdx.x * 256 + threadIdx.x;   // 32*128 = 4096
    if (idx >= 32 * 128) return;
    const int k = idx >> 7, j = idx & 127;
    W1pq[idx] = (j < 64) ? mW1[k * 64 + j] : mW1[(36 + k) * 64 + (j - 64)];
}

// ---------- factored edge MLP: 4 edges/wave, 16 lanes/edge, fp16 PQ gather ----------
__global__ __launch_bounds__(256) void edge_mlp_fast2(const __half* __restrict__ PQ,     // [N,128] fp16
                                                      const float* __restrict__ alpha_p, // [E,4] CSR raw w
                                                      const float* __restrict__ inv_s,   // [N,4]
                                                      const int* __restrict__ psrc,
                                                      const int* __restrict__ pdst,
                                                      const int* __restrict__ perm,
                                                      const float* __restrict__ mW1,     // rows 32..35
                                                      const float* __restrict__ mb1,
                                                      const float* __restrict__ mW2,
                                                      const float* __restrict__ mb2,
                                                      float* __restrict__ out) {         // [E,2]
    const int lane = threadIdx.x & 63, wv = threadIdx.x >> 6;
    const int g = lane >> 4, c = lane & 15;

    const float4 wa0 = *(const float4*)&mW1[32 * 64 + c * 4];
    const float4 wa1 = *(const float4*)&mW1[33 * 64 + c * 4];
    const float4 wa2 = *(const float4*)&mW1[34 * 64 + c * 4];
    const float4 wa3 = *(const float4*)&mW1[35 * 64 + c * 4];
    const float4 b1v = *(const float4*)&mb1[c * 4];
    const float4 w2a = *(const float4*)&mW2[c * 8];
    const float4 w2b = *(const float4*)&mW2[c * 8 + 4];
    const float bo0 = mb2[0], bo1 = mb2[1];

    const h4* PQ4 = (const h4*)PQ;   // row stride 32 h4 units (128 halves)
    const int gw = blockIdx.x * 4 + wv;
    const int stride4 = gridDim.x * 4 * 4;

    for (int jb = gw * 4; jb < EE; jb += stride4) {
        const int j = jb + g;
        const int s = psrc[j];
        const int d = pdst[j];
        const float4 ar = *(const float4*)&alpha_p[(size_t)j * 4];
        const float4 iv = *(const float4*)&inv_s[(size_t)d * 4];
        const float al0 = ar.x * iv.x, al1 = ar.y * iv.y;
        const float al2 = ar.z * iv.z, al3 = ar.w * iv.w;
        const h4 ph = PQ4[(size_t)s * 32 + c];
        const h4 qh = PQ4[(size_t)d * 32 + 16 + c];
        const float2 pl = __half22float2(ph.a), pm = __half22float2(ph.b);
        const float2 ql = __half22float2(qh.a), qm = __half22float2(qh.b);
        float4 h;
        h.x = pl.x + ql.x + b1v.x; h.y = pl.y + ql.y + b1v.y;
        h.z = pm.x + qm.x + b1v.z; h.w = pm.y + qm.y + b1v.w;
        h.x = fmaf(al0, wa0.x, h.x); h.y = fmaf(al0, wa0.y, h.y);
        h.z = fmaf(al0, wa0.z, h.z); h.w = fmaf(al0, wa0.w, h.w);
        h.x = fmaf(al1, wa1.x, h.x); h.y = fmaf(al1, wa1.y, h.y);
        h.z = fmaf(al1, wa1.z, h.z); h.w = fmaf(al1, wa1.w, h.w);
        h.x = fmaf(al2, wa2.x, h.x); h.y = fmaf(al2, wa2.y, h.y);
        h.z = fmaf(al2, wa2.z, h.z); h.w = fmaf(al2, wa2.w, h.w);
        h.x = fmaf(al3, wa3.x, h.x); h.y = fmaf(al3, wa3.y, h.y);
        h.z = fmaf(al3, wa3.z, h.z); h.w = fmaf(al3, wa3.w, h.w);
        h.x = fmaxf(h.x, 0.f); h.y = fmaxf(h.y, 0.f);
        h.z = fmaxf(h.z, 0.f); h.w = fmaxf(h.w, 0.f);

        float v0 = h.x * w2a.x + h.y * w2a.z + h.z * w2b.x + h.w * w2b.z;
        float v1 = h.x * w2a.y + h.y * w2a.w + h.z * w2b.y + h.w * w2b.w;
        #pragma unroll
        for (int msk = 1; msk < 16; msk <<= 1) {
            v0 += __shfl_xor(v0, msk, 64);
            v1 += __shfl_xor(v1, msk, 64);
        }
        if (c == 0)
            *(float2*)&out[(size_t)perm[j] * 2] = make_float2(v0 + bo0, v1 + bo1);
    }
}

extern "C" void kernel_launch(void* const* d_in, const int* in_sizes, int n_in,
                              void* d_out, int out_size, void* d_ws, size_t ws_size,
                              hipStream_t stream) {
    const float* x        = (const float*)d_in[0];
    const int*   ei       = (const int*)d_in[1];
    // d_in[2] edge_attr: unused (edge_dim=None). d_in[3] flag: unused.
    const float* W1       = (const float*)d_in[4];
    const float* att1_src = (const float*)d_in[5];
    const float* att1_dst = (const float*)d_in[6];
    const float* b1       = (const float*)d_in[7];
    const float* W3       = (const float*)d_in[8];
    const float* att3_src = (const float*)d_in[9];
    const float* att3_dst = (const float*)d_in[10];
    const float* b3       = (const float*)d_in[11];
    const float* mW1      = (const float*)d_in[12];
    const float* mb1      = (const float*)d_in[13];
    const float* mW2      = (const float*)d_in[14];
    const float* mb2      = (const float*)d_in[15];

    float* out_nodes = (float*)d_out;               // [N,32]
    float* out_edges = out_nodes + (size_t)NN * 32; // [E,2]

    // workspace layout (floats/ints)
    float* ws = (float*)d_ws;
    __half*   xlh     = (__half*)ws;                  // N*256 halves (layer-1 GEMM out)
    float*    xl2     = ws;                           // N*128 fp32 (layer-2 GEMM out)
    __half*   PQh     = (__half*)ws;                  // N*128 halves, after xl2 dead
    float*    h1      = ws + 12800000;                // N*64
    float*    alpha_p = ws + 16000000;                // E*4 (CSR-order raw w, layer 2)
    float*    a_s     = ws + 25600000;                // N*4
    float*    a_d     = ws + 25800000;                // N*4
    float*    W1pq    = ws + 26000000;                // 32*128
    float*    inv_s   = ws + 26100000;                // N*4  (1/softmax-denominator, layer 2)
    int*      deg     = (int*)(ws + 26400000);        // N
    int*      cursor  = (int*)(ws + 26450000);        // N
    int*      rowptr  = (int*)(ws + 26500000);        // N+1
    int*      perm    = (int*)(ws + 26550008);        // E
    int*      psrc    = (int*)(ws + 27350008);        // E
    int*      pdst    = (int*)(ws + 28150008);        // E

    const int gemmRows = (NN + 63) / 64;  // 782
    const int EB = (EE + 255) / 256;      // 3125
    const int NB4 = (NN + 3) / 4;         // wave-per-node blocks (4 waves/block)

    // ======== CSR build (shared by both layers) ========
    hipMemsetAsync(deg, 0, (size_t)NN * 4, stream);
    count_deg_k<<<EB, 256, 0, stream>>>(ei, deg);
    scan_k<<<1, 1024, 0, stream>>>(deg, rowptr, cursor);
    scatter_perm_k<<<EB, 256, 0, stream>>>(ei, cursor, perm, psrc, pdst);
    pack_w1<<<16, 256, 0, stream>>>(mW1, W1pq);

    // ======== Layer 1 (C=64, HC=256): xl stored fp16, scores from fp32 acc ========
    gemm_att<64, true><<<dim3(gemmRows, 4), 256, 0, stream>>>(x, W1, xlh, att1_src, att1_dst,
                                                              a_s, a_d, NN, INF, NH * 64);
    softagg1h<<<NB4, 256, 0, stream>>>(rowptr, psrc, a_s, a_d, xlh, b1, h1);

    // ======== Layer 2 (C=32, HC=128): fp32 (feeds final node outputs) ========
    gemm_att<32, false><<<dim3(gemmRows, 2), 256, 0, stream>>>(h1, W3, xl2, att3_src, att3_dst,
                                                               a_s, a_d, NN, 64, NH * 32);
    softagg2<<<NB4, 256, 0, stream>>>(rowptr, psrc, a_s, a_d, alpha_p, inv_s, xl2, b3,
                                      out_nodes);

    // ======== Edge MLP (factored): PQ = out_nodes @ [W1[0:32] | W1[36:68]], fp16 ========
    // xl2 is dead after softagg2 -> reuse its region for PQ.
    gemm_pq_half<<<dim3(gemmRows, 2), 256, 0, stream>>>(out_nodes, W1pq, PQh, NN, 32, 128);
    edge_mlp_fast2<<<2048, 256, 0, stream>>>(PQh, alpha_p, inv_s, psrc, pdst, perm,
                                             mW1, mb1, mW2, mb2, out_edges);
}

// Round 4
// 482.714 us; speedup vs baseline: 1.1784x; 1.0451x over previous
//
#include <hip/hip_runtime.h>
#include <hip/hip_fp16.h>

// Problem constants
constexpr int NN   = 50000;
constexpr int EE   = 800000;
constexpr int INF  = 128;   // input feat
constexpr int NH   = 4;     // heads

struct __align__(8) h4 { __half2 a, b; };   // 4 halves = 8 bytes

__device__ __forceinline__ float elw(float a) {
    a = (a > 0.f) ? a : 0.2f * a;          // leaky_relu(0.2)
    return __expf(a);                       // exp without max-sub (scores bounded)
}

// ---------- Tiled fp32 GEMM (64x64, 4x4) with fp16 output: PQ GEMM ----------
__global__ __launch_bounds__(256) void gemm_pq_half(const float* __restrict__ A,
                                                    const float* __restrict__ B,
                                                    __half* __restrict__ C,
                                                    int N, int K, int M) {
    __shared__ float As[16][68];   // [k][row], padded
    __shared__ float Bs[16][64];   // [k][col]
    const int tid = threadIdx.x;
    const int tx = tid & 15, ty = tid >> 4;
    const int row0 = blockIdx.x * 64, col0 = blockIdx.y * 64;

    float acc[4][4] = {};

    for (int k0 = 0; k0 < K; k0 += 16) {
        {
            const int a_row = tid >> 2;
            const int a_k   = (tid & 3) * 4;
            const int gr    = row0 + a_row;
            float4 v = make_float4(0.f, 0.f, 0.f, 0.f);
            if (gr < N) v = *(const float4*)(A + (size_t)gr * K + k0 + a_k);
            As[a_k + 0][a_row] = v.x;
            As[a_k + 1][a_row] = v.y;
            As[a_k + 2][a_row] = v.z;
            As[a_k + 3][a_row] = v.w;
        }
        {
            const int b_k = tid >> 4;
            const int b_c = (tid & 15) * 4;
            float4 w = *(const float4*)(B + (size_t)(k0 + b_k) * M + col0 + b_c);
            *(float4*)&Bs[b_k][b_c] = w;
        }
        __syncthreads();
        #pragma unroll
        for (int kk = 0; kk < 16; ++kk) {
            float4 a = *(const float4*)&As[kk][ty * 4];
            float4 b = *(const float4*)&Bs[kk][tx * 4];
            const float av[4] = {a.x, a.y, a.z, a.w};
            const float bv[4] = {b.x, b.y, b.z, b.w};
            #pragma unroll
            for (int i = 0; i < 4; ++i)
                #pragma unroll
                for (int j = 0; j < 4; ++j)
                    acc[i][j] = fmaf(av[i], bv[j], acc[i][j]);
        }
        __syncthreads();
    }
    #pragma unroll
    for (int i = 0; i < 4; ++i) {
        const int r = row0 + ty * 4 + i;
        if (r < N) {
            __half* cp = C + (size_t)r * M + col0 + tx * 4;
            __half2 q0 = __halves2half2(__float2half_rn(acc[i][0]), __float2half_rn(acc[i][1]));
            __half2 q1 = __halves2half2(__float2half_rn(acc[i][2]), __float2half_rn(acc[i][3]));
            *(__half2*)cp       = q0;
            *(__half2*)(cp + 2) = q1;
        }
    }
}

// ---------- Tiled fp32 GEMM (64-tile) with fused attention-score epilogue ----------
// HOUT: store C as fp16. Attention scores always computed from fp32 acc.
template <int CH, bool HOUT>
__global__ __launch_bounds__(256) void gemm_att(const float* __restrict__ A,
                                                const float* __restrict__ B,
                                                void* __restrict__ Cv,
                                                const float* __restrict__ att_s,
                                                const float* __restrict__ att_d,
                                                float* __restrict__ a_s,
                                                float* __restrict__ a_d,
                                                int N, int K, int M) {
    __shared__ float As[16][68];   // [k][row], padded
    __shared__ float Bs[16][64];   // [k][col]
    const int tid = threadIdx.x;
    const int tx = tid & 15, ty = tid >> 4;
    const int row0 = blockIdx.x * 64, col0 = blockIdx.y * 64;

    const int col  = col0 + tx * 4;
    const int head = col / CH;
    const int pos  = col % CH;
    float attS[4], attD[4];
    #pragma unroll
    for (int j = 0; j < 4; ++j) {
        attS[j] = att_s[head * CH + pos + j];
        attD[j] = att_d[head * CH + pos + j];
    }

    float acc[4][4] = {};

    for (int k0 = 0; k0 < K; k0 += 16) {
        {
            const int a_row = tid >> 2;
            const int a_k   = (tid & 3) * 4;
            const int gr    = row0 + a_row;
            float4 v = make_float4(0.f, 0.f, 0.f, 0.f);
            if (gr < N) v = *(const float4*)(A + (size_t)gr * K + k0 + a_k);
            As[a_k + 0][a_row] = v.x;
            As[a_k + 1][a_row] = v.y;
            As[a_k + 2][a_row] = v.z;
            As[a_k + 3][a_row] = v.w;
        }
        {
            const int b_k = tid >> 4;
            const int b_c = (tid & 15) * 4;
            float4 w = *(const float4*)(B + (size_t)(k0 + b_k) * M + col0 + b_c);
            *(float4*)&Bs[b_k][b_c] = w;
        }
        __syncthreads();
        #pragma unroll
        for (int kk = 0; kk < 16; ++kk) {
            float4 a = *(const float4*)&As[kk][ty * 4];
            float4 b = *(const float4*)&Bs[kk][tx * 4];
            const float av[4] = {a.x, a.y, a.z, a.w};
            const float bv[4] = {b.x, b.y, b.z, b.w};
            #pragma unroll
            for (int i = 0; i < 4; ++i)
                #pragma unroll
                for (int j = 0; j < 4; ++j)
                    acc[i][j] = fmaf(av[i], bv[j], acc[i][j]);
        }
        __syncthreads();
    }
    #pragma unroll
    for (int i = 0; i < 4; ++i) {
        const int r = row0 + ty * 4 + i;
        if (r < N) {
            if constexpr (HOUT) {
                __half* C  = (__half*)Cv;
                __half* cp = C + (size_t)r * M + col0 + tx * 4;
                __half2 q0 = __halves2half2(__float2half_rn(acc[i][0]), __float2half_rn(acc[i][1]));
                __half2 q1 = __halves2half2(__float2half_rn(acc[i][2]), __float2half_rn(acc[i][3]));
                *(__half2*)cp       = q0;
                *(__half2*)(cp + 2) = q1;
            } else {
                float* C  = (float*)Cv;
                float* cp = C + (size_t)r * M + col0 + tx * 4;
                cp[0] = acc[i][0]; cp[1] = acc[i][1]; cp[2] = acc[i][2]; cp[3] = acc[i][3];
            }
        }
        float ss = 0.f, sd = 0.f;
        #pragma unroll
        for (int j = 0; j < 4; ++j) {
            ss = fmaf(acc[i][j], attS[j], ss);
            sd = fmaf(acc[i][j], attD[j], sd);
        }
        #pragma unroll
        for (int msk = 1; msk < CH / 4; msk <<= 1) {
            ss += __shfl_xor(ss, msk, 64);
            sd += __shfl_xor(sd, msk, 64);
        }
        if ((tx & (CH / 4 - 1)) == 0 && r < N) {
            a_s[r * NH + head] = ss;
            a_d[r * NH + head] = sd;
        }
    }
}

// ---------- CSR build ----------
__global__ __launch_bounds__(256) void count_deg_k(const int* __restrict__ ei,
                                                   int* __restrict__ deg) {
    const int e = blockIdx.x * 256 + threadIdx.x;
    if (e < EE) atomicAdd(&deg[ei[EE + e]], 1);
}

// single-block exclusive scan over deg[0..NN) -> rowptr[0..NN], cursor copy
__global__ __launch_bounds__(1024) void scan_k(const int* __restrict__ deg,
                                               int* __restrict__ rowptr,
                                               int* __restrict__ cursor) {
    __shared__ int wsum[16];
    const int tid = threadIdx.x;
    const int lane = tid & 63, wv = tid >> 6;
    int total = 0;
    for (int base = 0; base < NN; base += 1024) {
        const int i = base + tid;
        const int v = (i < NN) ? deg[i] : 0;
        int incl = v;
        #pragma unroll
        for (int d = 1; d < 64; d <<= 1) {
            int t = __shfl_up(incl, d, 64);
            if (lane >= d) incl += t;
        }
        if (lane == 63) wsum[wv] = incl;
        __syncthreads();
        if (wv == 0) {
            int s = (lane < 16) ? wsum[lane] : 0;
            #pragma unroll
            for (int d = 1; d < 16; d <<= 1) {
                int t = __shfl_up(s, d, 64);
                if (lane >= d) s += t;
            }
            if (lane < 16) wsum[lane] = s;
        }
        __syncthreads();
        const int excl = total + (wv > 0 ? wsum[wv - 1] : 0) + incl - v;
        const int chunk = wsum[15];
        if (i < NN) { rowptr[i] = excl; cursor[i] = excl; }
        total += chunk;
        __syncthreads();   // protect wsum before next iteration's writes
    }
    if (tid == 0) rowptr[NN] = total;
}

__global__ __launch_bounds__(256) void scatter_perm_k(const int* __restrict__ ei,
                                                      int* __restrict__ cursor,
                                                      int* __restrict__ perm,
                                                      int* __restrict__ psrc,
                                                      int* __restrict__ pdst) {
    const int e = blockIdx.x * 256 + threadIdx.x;
    if (e >= EE) return;
    const int d = ei[EE + e];
    const int p = atomicAdd(&cursor[d], 1);
    perm[p] = e;
    psrc[p] = ei[e];
    pdst[p] = d;
}

// ---------- Layer 1: SINGLE-PASS softmax+aggregate, fp16 xl payload, HC=256 ----------
// One wave per dst node; lane owns 4 channels (8 B/lane/edge).
__global__ __launch_bounds__(256) void softagg1h(const int* __restrict__ rowptr,
                                                 const int* __restrict__ psrc,
                                                 const float* __restrict__ a_s,
                                                 const float* __restrict__ a_d,
                                                 const __half* __restrict__ xl,
                                                 const float* __restrict__ bias,
                                                 float* __restrict__ out) {
    const int wv = threadIdx.x >> 6, lane = threadIdx.x & 63;
    const int n = blockIdx.x * 4 + wv;
    if (n >= NN) return;
    const int r0 = rowptr[n], r1 = rowptr[n + 1];
    const int hh = lane >> 4;
    const float ad = a_d[n * NH + hh];

    const h4* X = (const h4*)xl;   // row stride 64 h4 units (256 halves)
    float4 A0 = {0,0,0,0}, A1 = {0,0,0,0}, A2 = {0,0,0,0}, A3 = {0,0,0,0};
    float sum = 0.f;
    int j = r0;
    for (; j + 7 < r1; j += 8) {
        const int s0 = psrc[j],     s1 = psrc[j + 1], s2 = psrc[j + 2], s3 = psrc[j + 3];
        const int s4 = psrc[j + 4], s5 = psrc[j + 5], s6 = psrc[j + 6], s7 = psrc[j + 7];
        const float w0 = elw(a_s[s0 * NH + hh] + ad);
        const float w1 = elw(a_s[s1 * NH + hh] + ad);
        const float w2 = elw(a_s[s2 * NH + hh] + ad);
        const float w3 = elw(a_s[s3 * NH + hh] + ad);
        const float w4 = elw(a_s[s4 * NH + hh] + ad);
        const float w5 = elw(a_s[s5 * NH + hh] + ad);
        const float w6 = elw(a_s[s6 * NH + hh] + ad);
        const float w7 = elw(a_s[s7 * NH + hh] + ad);
        sum += ((w0 + w1) + (w2 + w3)) + ((w4 + w5) + (w6 + w7));
        const h4 v0 = X[(size_t)s0 * 64 + lane];
        const h4 v1 = X[(size_t)s1 * 64 + lane];
        const h4 v2 = X[(size_t)s2 * 64 + lane];
        const h4 v3 = X[(size_t)s3 * 64 + lane];
        const h4 v4 = X[(size_t)s4 * 64 + lane];
        const h4 v5 = X[(size_t)s5 * 64 + lane];
        const h4 v6 = X[(size_t)s6 * 64 + lane];
        const h4 v7 = X[(size_t)s7 * 64 + lane];
        float2 l0 = __half22float2(v0.a), m0 = __half22float2(v0.b);
        float2 l1 = __half22float2(v1.a), m1 = __half22float2(v1.b);
        float2 l2 = __half22float2(v2.a), m2 = __half22float2(v2.b);
        float2 l3 = __half22float2(v3.a), m3 = __half22float2(v3.b);
        float2 l4 = __half22float2(v4.a), m4 = __half22float2(v4.b);
        float2 l5 = __half22float2(v5.a), m5 = __half22float2(v5.b);
        float2 l6 = __half22float2(v6.a), m6 = __half22float2(v6.b);
        float2 l7 = __half22float2(v7.a), m7 = __half22float2(v7.b);
        A0.x = fmaf(w0, l0.x, A0.x); A0.y = fmaf(w0, l0.y, A0.y);
        A0.z = fmaf(w0, m0.x, A0.z); A0.w = fmaf(w0, m0.y, A0.w);
        A1.x = fmaf(w1, l1.x, A1.x); A1.y = fmaf(w1, l1.y, A1.y);
        A1.z = fmaf(w1, m1.x, A1.z); A1.w = fmaf(w1, m1.y, A1.w);
        A2.x = fmaf(w2, l2.x, A2.x); A2.y = fmaf(w2, l2.y, A2.y);
        A2.z = fmaf(w2, m2.x, A2.z); A2.w = fmaf(w2, m2.y, A2.w);
        A3.x = fmaf(w3, l3.x, A3.x); A3.y = fmaf(w3, l3.y, A3.y);
        A3.z = fmaf(w3, m3.x, A3.z); A3.w = fmaf(w3, m3.y, A3.w);
        A0.x = fmaf(w4, l4.x, A0.x); A0.y = fmaf(w4, l4.y, A0.y);
        A0.z = fmaf(w4, m4.x, A0.z); A0.w = fmaf(w4, m4.y, A0.w);
        A1.x = fmaf(w5, l5.x, A1.x); A1.y = fmaf(w5, l5.y, A1.y);
        A1.z = fmaf(w5, m5.x, A1.z); A1.w = fmaf(w5, m5.y, A1.w);
        A2.x = fmaf(w6, l6.x, A2.x); A2.y = fmaf(w6, l6.y, A2.y);
        A2.z = fmaf(w6, m6.x, A2.z); A2.w = fmaf(w6, m6.y, A2.w);
        A3.x = fmaf(w7, l7.x, A3.x); A3.y = fmaf(w7, l7.y, A3.y);
        A3.z = fmaf(w7, m7.x, A3.z); A3.w = fmaf(w7, m7.y, A3.w);
    }
    for (; j < r1; ++j) {
        const int s0 = psrc[j];
        const float w0 = elw(a_s[s0 * NH + hh] + ad);
        sum += w0;
        const h4 v0 = X[(size_t)s0 * 64 + lane];
        float2 l0 = __half22float2(v0.a), m0 = __half22float2(v0.b);
        A0.x = fmaf(w0, l0.x, A0.x); A0.y = fmaf(w0, l0.y, A0.y);
        A0.z = fmaf(w0, m0.x, A0.z); A0.w = fmaf(w0, m0.y, A0.w);
    }
    const float inv = 1.f / (sum + 1e-30f);
    float4 t;
    t.x = ((A0.x + A1.x) + (A2.x + A3.x)) * inv;
    t.y = ((A0.y + A1.y) + (A2.y + A3.y)) * inv;
    t.z = ((A0.z + A1.z) + (A2.z + A3.z)) * inv;
    t.w = ((A0.w + A1.w) + (A2.w + A3.w)) * inv;
    #pragma unroll
    for (int msk = 16; msk < 64; msk <<= 1) {
        t.x += __shfl_xor(t.x, msk, 64);
        t.y += __shfl_xor(t.y, msk, 64);
        t.z += __shfl_xor(t.z, msk, 64);
        t.w += __shfl_xor(t.w, msk, 64);
    }
    if (lane < 16) {
        const float4 b = ((const float4*)bias)[lane];
        float4 o;
        o.x = t.x * 0.25f + b.x; o.y = t.y * 0.25f + b.y;
        o.z = t.z * 0.25f + b.z; o.w = t.w * 0.25f + b.w;
        ((float4*)out)[(size_t)n * 16 + lane] = o;
    }
}

// ---------- Layer 2: SINGLE-PASS softmax+aggregate, fp16 xl2 payload, HC=128 ----------
// Half-wave (32 lanes) per edge, 8 B/lane/edge. Raw w -> alpha_p, 1/sum -> inv_s.
// fp32 accumulation: node-output error from fp16 payload is a convex combo of
// ~2e-4 rms roundings, ÷4 head-mean -> ~1e-4 rms, below the edge-path absmax.
__global__ __launch_bounds__(256) void softagg2h(const int* __restrict__ rowptr,
                                                 const int* __restrict__ psrc,
                                                 const float* __restrict__ a_s,
                                                 const float* __restrict__ a_d,
                                                 float* __restrict__ alpha_p,
                                                 float* __restrict__ inv_s,
                                                 const __half* __restrict__ xl,
                                                 const float* __restrict__ bias,
                                                 float* __restrict__ out) {
    const int wv = threadIdx.x >> 6, lane = threadIdx.x & 63;
    const int n = blockIdx.x * 4 + wv;
    if (n >= NN) return;
    const int r0 = rowptr[n], r1 = rowptr[n + 1];
    const int cl = lane & 31, half = lane >> 5, hh = cl >> 3;
    const float ad = a_d[n * NH + hh];
    const bool writer = (cl & 7) == 0;   // one lane per (half, head) writes raw w

    const h4* X = (const h4*)xl;   // row stride 32 h4 units (128 halves)
    float4 A0 = {0,0,0,0}, A1 = {0,0,0,0};
    float sum = 0.f;
    int j = r0;
    for (; j + 7 < r1; j += 8) {
        const int ja = j + half, jc = j + 2 + half, je = j + 4 + half, jg = j + 6 + half;
        const int sa = psrc[ja], sc = psrc[jc], se = psrc[je], sg = psrc[jg];
        const float wa = elw(a_s[sa * NH + hh] + ad);
        const float wc = elw(a_s[sc * NH + hh] + ad);
        const float we = elw(a_s[se * NH + hh] + ad);
        const float wg = elw(a_s[sg * NH + hh] + ad);
        if (writer) {
            alpha_p[ja * NH + hh] = wa; alpha_p[jc * NH + hh] = wc;
            alpha_p[je * NH + hh] = we; alpha_p[jg * NH + hh] = wg;
        }
        sum += (wa + wc) + (we + wg);
        const h4 va = X[(size_t)sa * 32 + cl];
        const h4 vc = X[(size_t)sc * 32 + cl];
        const h4 ve = X[(size_t)se * 32 + cl];
        const h4 vg = X[(size_t)sg * 32 + cl];
        const float2 la = __half22float2(va.a), ma = __half22float2(va.b);
        const float2 lc = __half22float2(vc.a), mc = __half22float2(vc.b);
        const float2 le = __half22float2(ve.a), me = __half22float2(ve.b);
        const float2 lg = __half22float2(vg.a), mg = __half22float2(vg.b);
        A0.x = fmaf(wa, la.x, A0.x); A0.y = fmaf(wa, la.y, A0.y);
        A0.z = fmaf(wa, ma.x, A0.z); A0.w = fmaf(wa, ma.y, A0.w);
        A1.x = fmaf(wc, lc.x, A1.x); A1.y = fmaf(wc, lc.y, A1.y);
        A1.z = fmaf(wc, mc.x, A1.z); A1.w = fmaf(wc, mc.y, A1.w);
        A0.x = fmaf(we, le.x, A0.x); A0.y = fmaf(we, le.y, A0.y);
        A0.z = fmaf(we, me.x, A0.z); A0.w = fmaf(we, me.y, A0.w);
        A1.x = fmaf(wg, lg.x, A1.x); A1.y = fmaf(wg, lg.y, A1.y);
        A1.z = fmaf(wg, mg.x, A1.z); A1.w = fmaf(wg, mg.y, A1.w);
    }
    for (; j < r1; j += 2) {
        const int ja = j + half;
        const bool valid = ja < r1;
        const int sa = psrc[valid ? ja : r0];
        float wa = 0.f;
        if (valid) {
            wa = elw(a_s[sa * NH + hh] + ad);
            if (writer) alpha_p[ja * NH + hh] = wa;
        }
        sum += wa;
        const h4 va = X[(size_t)sa * 32 + cl];
        const float2 la = __half22float2(va.a), ma = __half22float2(va.b);
        A0.x = fmaf(wa, la.x, A0.x); A0.y = fmaf(wa, la.y, A0.y);
        A0.z = fmaf(wa, ma.x, A0.z); A0.w = fmaf(wa, ma.y, A0.w);
    }
    // merge halves' partial sums, then normalize
    sum += __shfl_xor(sum, 32, 64);
    const float inv = 1.f / (sum + 1e-30f);
    if (writer && half == 0) inv_s[n * NH + hh] = inv;

    float4 t;
    t.x = A0.x + A1.x; t.y = A0.y + A1.y; t.z = A0.z + A1.z; t.w = A0.w + A1.w;
    t.x += __shfl_xor(t.x, 32, 64);
    t.y += __shfl_xor(t.y, 32, 64);
    t.z += __shfl_xor(t.z, 32, 64);
    t.w += __shfl_xor(t.w, 32, 64);
    t.x *= inv; t.y *= inv; t.z *= inv; t.w *= inv;
    #pragma unroll
    for (int q = 0; q < 2; ++q) {
        const int msk = (q == 0) ? 8 : 16;
        t.x += __shfl_xor(t.x, msk, 64);
        t.y += __shfl_xor(t.y, msk, 64);
        t.z += __shfl_xor(t.z, msk, 64);
        t.w += __shfl_xor(t.w, msk, 64);
    }
    if (lane < 8) {
        const float4 b = ((const float4*)bias)[lane];
        float4 o;
        o.x = t.x * 0.25f + b.x; o.y = t.y * 0.25f + b.y;
        o.z = t.z * 0.25f + b.z; o.w = t.w * 0.25f + b.w;
        ((float4*)out)[(size_t)n * 8 + lane] = o;
    }
}

// ---------- pack W1 src/dst row-blocks into [32][128] for the PQ GEMM ----------
__global__ __launch_bounds__(256) void pack_w1(const float* __restrict__ mW1,
                                               float* __restrict__ W1pq) {
    const int idx = blockIdx.x * 256 + threadIdx.x;   // 32*128 = 4096
    if (idx >= 32 * 128) return;
    const int k = idx >> 7, j = idx & 127;
    W1pq[idx] = (j < 64) ? mW1[k * 64 + j] : mW1[(36 + k) * 64 + (j - 64)];
}

// ---------- factored edge MLP: 4 edges/wave, 16 lanes/edge, fp16 PQ gather ----------
__global__ __launch_bounds__(256) void edge_mlp_fast2(const __half* __restrict__ PQ,     // [N,128] fp16
                                                      const float* __restrict__ alpha_p, // [E,4] CSR raw w
                                                      const float* __restrict__ inv_s,   // [N,4]
                                                      const int* __restrict__ psrc,
                                                      const int* __restrict__ pdst,
                                                      const int* __restrict__ perm,
                                                      const float* __restrict__ mW1,     // rows 32..35
                                                      const float* __restrict__ mb1,
                                                      const float* __restrict__ mW2,
                                                      const float* __restrict__ mb2,
                                                      float* __restrict__ out) {         // [E,2]
    const int lane = threadIdx.x & 63, wv = threadIdx.x >> 6;
    const int g = lane >> 4, c = lane & 15;

    const float4 wa0 = *(const float4*)&mW1[32 * 64 + c * 4];
    const float4 wa1 = *(const float4*)&mW1[33 * 64 + c * 4];
    const float4 wa2 = *(const float4*)&mW1[34 * 64 + c * 4];
    const float4 wa3 = *(const float4*)&mW1[35 * 64 + c * 4];
    const float4 b1v = *(const float4*)&mb1[c * 4];
    const float4 w2a = *(const float4*)&mW2[c * 8];
    const float4 w2b = *(const float4*)&mW2[c * 8 + 4];
    const float bo0 = mb2[0], bo1 = mb2[1];

    const h4* PQ4 = (const h4*)PQ;   // row stride 32 h4 units (128 halves)
    const int gw = blockIdx.x * 4 + wv;
    const int stride4 = gridDim.x * 4 * 4;

    for (int jb = gw * 4; jb < EE; jb += stride4) {
        const int j = jb + g;
        const int s = psrc[j];
        const int d = pdst[j];
        const float4 ar = *(const float4*)&alpha_p[(size_t)j * 4];
        const float4 iv = *(const float4*)&inv_s[(size_t)d * 4];
        const float al0 = ar.x * iv.x, al1 = ar.y * iv.y;
        const float al2 = ar.z * iv.z, al3 = ar.w * iv.w;
        const h4 ph = PQ4[(size_t)s * 32 + c];
        const h4 qh = PQ4[(size_t)d * 32 + 16 + c];
        const float2 pl = __half22float2(ph.a), pm = __half22float2(ph.b);
        const float2 ql = __half22float2(qh.a), qm = __half22float2(qh.b);
        float4 h;
        h.x = pl.x + ql.x + b1v.x; h.y = pl.y + ql.y + b1v.y;
        h.z = pm.x + qm.x + b1v.z; h.w = pm.y + qm.y + b1v.w;
        h.x = fmaf(al0, wa0.x, h.x); h.y = fmaf(al0, wa0.y, h.y);
        h.z = fmaf(al0, wa0.z, h.z); h.w = fmaf(al0, wa0.w, h.w);
        h.x = fmaf(al1, wa1.x, h.x); h.y = fmaf(al1, wa1.y, h.y);
        h.z = fmaf(al1, wa1.z, h.z); h.w = fmaf(al1, wa1.w, h.w);
        h.x = fmaf(al2, wa2.x, h.x); h.y = fmaf(al2, wa2.y, h.y);
        h.z = fmaf(al2, wa2.z, h.z); h.w = fmaf(al2, wa2.w, h.w);
        h.x = fmaf(al3, wa3.x, h.x); h.y = fmaf(al3, wa3.y, h.y);
        h.z = fmaf(al3, wa3.z, h.z); h.w = fmaf(al3, wa3.w, h.w);
        h.x = fmaxf(h.x, 0.f); h.y = fmaxf(h.y, 0.f);
        h.z = fmaxf(h.z, 0.f); h.w = fmaxf(h.w, 0.f);

        float v0 = h.x * w2a.x + h.y * w2a.z + h.z * w2b.x + h.w * w2b.z;
        float v1 = h.x * w2a.y + h.y * w2a.w + h.z * w2b.y + h.w * w2b.w;
        #pragma unroll
        for (int msk = 1; msk < 16; msk <<= 1) {
            v0 += __shfl_xor(v0, msk, 64);
            v1 += __shfl_xor(v1, msk, 64);
        }
        if (c == 0)
            *(float2*)&out[(size_t)perm[j] * 2] = make_float2(v0 + bo0, v1 + bo1);
    }
}

extern "C" void kernel_launch(void* const* d_in, const int* in_sizes, int n_in,
                              void* d_out, int out_size, void* d_ws, size_t ws_size,
                              hipStream_t stream) {
    const float* x        = (const float*)d_in[0];
    const int*   ei       = (const int*)d_in[1];
    // d_in[2] edge_attr: unused (edge_dim=None). d_in[3] flag: unused.
    const float* W1       = (const float*)d_in[4];
    const float* att1_src = (const float*)d_in[5];
    const float* att1_dst = (const float*)d_in[6];
    const float* b1       = (const float*)d_in[7];
    const float* W3       = (const float*)d_in[8];
    const float* att3_src = (const float*)d_in[9];
    const float* att3_dst = (const float*)d_in[10];
    const float* b3       = (const float*)d_in[11];
    const float* mW1      = (const float*)d_in[12];
    const float* mb1      = (const float*)d_in[13];
    const float* mW2      = (const float*)d_in[14];
    const float* mb2      = (const float*)d_in[15];

    float* out_nodes = (float*)d_out;               // [N,32]
    float* out_edges = out_nodes + (size_t)NN * 32; // [E,2]

    // workspace layout (floats/ints)
    float* ws = (float*)d_ws;
    __half*   xlh     = (__half*)ws;                  // N*256 halves (layer-1 GEMM out)
    __half*   xl2h    = (__half*)ws;                  // N*128 halves (layer-2 GEMM out)
    __half*   PQh     = (__half*)ws;                  // N*128 halves, after xl2h dead
    float*    h1      = ws + 12800000;                // N*64
    float*    alpha_p = ws + 16000000;                // E*4 (CSR-order raw w, layer 2)
    float*    a_s     = ws + 25600000;                // N*4
    float*    a_d     = ws + 25800000;                // N*4
    float*    W1pq    = ws + 26000000;                // 32*128
    float*    inv_s   = ws + 26100000;                // N*4  (1/softmax-denominator, layer 2)
    int*      deg     = (int*)(ws + 26400000);        // N
    int*      cursor  = (int*)(ws + 26450000);        // N
    int*      rowptr  = (int*)(ws + 26500000);        // N+1
    int*      perm    = (int*)(ws + 26550008);        // E
    int*      psrc    = (int*)(ws + 27350008);        // E
    int*      pdst    = (int*)(ws + 28150008);        // E

    const int gemmRows = (NN + 63) / 64;  // 782
    const int EB = (EE + 255) / 256;      // 3125
    const int NB4 = (NN + 3) / 4;         // wave-per-node blocks (4 waves/block)

    // ======== CSR build (shared by both layers) ========
    hipMemsetAsync(deg, 0, (size_t)NN * 4, stream);
    count_deg_k<<<EB, 256, 0, stream>>>(ei, deg);
    scan_k<<<1, 1024, 0, stream>>>(deg, rowptr, cursor);
    scatter_perm_k<<<EB, 256, 0, stream>>>(ei, cursor, perm, psrc, pdst);
    pack_w1<<<16, 256, 0, stream>>>(mW1, W1pq);

    // ======== Layer 1 (C=64, HC=256): xl stored fp16, scores from fp32 acc ========
    gemm_att<64, true><<<dim3(gemmRows, 4), 256, 0, stream>>>(x, W1, xlh, att1_src, att1_dst,
                                                              a_s, a_d, NN, INF, NH * 64);
    softagg1h<<<NB4, 256, 0, stream>>>(rowptr, psrc, a_s, a_d, xlh, b1, h1);

    // ======== Layer 2 (C=32, HC=128): xl2 stored fp16, fp32 accumulation ========
    gemm_att<32, true><<<dim3(gemmRows, 2), 256, 0, stream>>>(h1, W3, xl2h, att3_src, att3_dst,
                                                              a_s, a_d, NN, 64, NH * 32);
    softagg2h<<<NB4, 256, 0, stream>>>(rowptr, psrc, a_s, a_d, alpha_p, inv_s, xl2h, b3,
                                       out_nodes);

    // ======== Edge MLP (factored): PQ = out_nodes @ [W1[0:32] | W1[36:68]], fp16 ========
    // xl2h is dead after softagg2h -> reuse its region for PQ.
    gemm_pq_half<<<dim3(gemmRows, 2), 256, 0, stream>>>(out_nodes, W1pq, PQh, NN, 32, 128);
    edge_mlp_fast2<<<2048, 256, 0, stream>>>(PQh, alpha_p, inv_s, psrc, pdst, perm,
                                             mW1, mb1, mW2, mb2, out_edges);
}